// Round 1
// baseline (531.715 us; speedup 1.0000x reference)
//
#include <hip/hip_runtime.h>
#include <math.h>

#define N_NODES 20000
#define N_EDGES 320000
#define D_FEAT 256

// ---------------- GEMM: C[M,256] = A[M,256] @ B[256,256] + bias ----------------
__global__ __launch_bounds__(256) void gemm256(const float* __restrict__ A,
                                               const float* __restrict__ B,
                                               const float* __restrict__ bias,
                                               float* __restrict__ C, int M)
{
    __shared__ float As[16][68];   // transposed A tile: As[k][row]
    __shared__ float Bs[16][64];
    const int tid  = threadIdx.x;
    const int row0 = blockIdx.x * 64;
    const int col0 = blockIdx.y * 64;
    const int tr = (tid >> 4) * 4;     // micro-tile row 0..60
    const int tc = (tid & 15) * 4;     // micro-tile col
    const int lr = tid >> 2;           // A load row 0..63
    const int lk = (tid & 3) * 4;      // A load k-offset 0,4,8,12
    const int br = tid >> 4;           // B load k-row 0..15
    const int bc = (tid & 15) * 4;     // B load col offset

    float acc[4][4] = {};
    for (int k0 = 0; k0 < 256; k0 += 16) {
        float4 av = make_float4(0.f, 0.f, 0.f, 0.f);
        const int ga = row0 + lr;
        if (ga < M) av = *(const float4*)(A + (size_t)ga * 256 + k0 + lk);
        const float4 bv = *(const float4*)(B + (size_t)(k0 + br) * 256 + col0 + bc);
        __syncthreads();               // previous iteration's compute done
        As[lk + 0][lr] = av.x; As[lk + 1][lr] = av.y;
        As[lk + 2][lr] = av.z; As[lk + 3][lr] = av.w;
        *(float4*)&Bs[br][bc] = bv;
        __syncthreads();
#pragma unroll
        for (int kk = 0; kk < 16; ++kk) {
            const float4 a = *(const float4*)&As[kk][tr];
            const float4 b = *(const float4*)&Bs[kk][tc];
            const float aa[4] = {a.x, a.y, a.z, a.w};
            const float bb[4] = {b.x, b.y, b.z, b.w};
#pragma unroll
            for (int i = 0; i < 4; ++i)
#pragma unroll
                for (int j = 0; j < 4; ++j)
                    acc[i][j] += aa[i] * bb[j];
        }
    }
    const float4 bb4 = *(const float4*)(bias + col0 + tc);
    const float badd[4] = {bb4.x, bb4.y, bb4.z, bb4.w};
#pragma unroll
    for (int i = 0; i < 4; ++i) {
        const int gr = row0 + tr + i;
        if (gr < M) {
            float4 o;
            o.x = acc[i][0] + badd[0];
            o.y = acc[i][1] + badd[1];
            o.z = acc[i][2] + badd[2];
            o.w = acc[i][3] + badd[3];
            *(float4*)(C + (size_t)gr * 256 + col0 + tc) = o;
        }
    }
}

// ---------------- CSR build ----------------
__global__ void count_deg(const int* __restrict__ dst, int* __restrict__ deg)
{
    const int e = blockIdx.x * 256 + threadIdx.x;
    if (e < N_EDGES) atomicAdd(&deg[dst[e]], 1);
}

__global__ __launch_bounds__(1024) void scan_k(const int* __restrict__ deg,
                                               int* __restrict__ row_start)
{
    __shared__ int buf[1024];
    __shared__ int carry_s;
    const int tid = threadIdx.x;
    if (tid == 0) { carry_s = 0; row_start[0] = 0; }
    __syncthreads();
    for (int base = 0; base < N_NODES; base += 1024) {
        const int i = base + tid;
        buf[tid] = (i < N_NODES) ? deg[i] : 0;
        __syncthreads();
        for (int offd = 1; offd < 1024; offd <<= 1) {
            const int t = (tid >= offd) ? buf[tid - offd] : 0;
            __syncthreads();
            buf[tid] += t;
            __syncthreads();
        }
        const int inc = buf[tid] + carry_s;
        if (i < N_NODES) row_start[i + 1] = inc;
        __syncthreads();
        if (tid == 1023) carry_s = inc;
        __syncthreads();
    }
}

__global__ void fill_csr(const int* __restrict__ dst, const int* __restrict__ row_start,
                         int* __restrict__ cursor, int* __restrict__ edge_ids)
{
    const int e = blockIdx.x * 256 + threadIdx.x;
    if (e < N_EDGES) {
        const int d = dst[e];
        const int p = atomicAdd(&cursor[d], 1);
        edge_ids[row_start[d] + p] = e;
    }
}

// ---------------- attention: one wave per destination node ----------------
__global__ __launch_bounds__(256) void attn_k(const float* __restrict__ q,
                                              const float* __restrict__ k,
                                              const float* __restrict__ v,
                                              const float* __restrict__ ea,
                                              const float* __restrict__ We,
                                              const int* __restrict__ src,
                                              const int* __restrict__ row_start,
                                              const int* __restrict__ edge_ids,
                                              float* __restrict__ alpha_buf,
                                              float* __restrict__ out)
{
    const int wid  = threadIdx.x >> 6;
    const int lane = threadIdx.x & 63;
    const int n = blockIdx.x * 4 + wid;
    if (n >= N_NODES) return;

    const float4 qf  = *(const float4*)(q + (size_t)n * 256 + lane * 4);
    const float4 we4 = *(const float4*)(We + lane * 4);
    const int rs = row_start[n], re = row_start[n + 1];
    const int head = lane >> 4;

    float m = -1e30f;
    for (int s = rs; s < re; ++s) {
        const int e  = edge_ids[s];
        const int sn = src[e];
        const float a = ea[e];
        const float4 kf = *(const float4*)(k + (size_t)sn * 256 + lane * 4);
        float p = qf.x * (kf.x + a * we4.x) + qf.y * (kf.y + a * we4.y)
                + qf.z * (kf.z + a * we4.z) + qf.w * (kf.w + a * we4.w);
        p += __shfl_xor(p, 1);
        p += __shfl_xor(p, 2);
        p += __shfl_xor(p, 4);
        p += __shfl_xor(p, 8);
        p *= 0.125f;                       // 1/sqrt(64)
        if ((lane & 15) == 0) alpha_buf[(size_t)s * 4 + head] = p;
        m = fmaxf(m, p);
    }

    float ssum = 0.f;
    float ax = 0.f, ay = 0.f, az = 0.f, aw = 0.f;
    for (int s = rs; s < re; ++s) {
        const int e  = edge_ids[s];
        const int sn = src[e];
        const float a = ea[e];
        const float al = alpha_buf[(size_t)s * 4 + head];
        const float w = __expf(al - m);
        ssum += w;
        const float4 vf = *(const float4*)(v + (size_t)sn * 256 + lane * 4);
        ax += w * (vf.x + a * we4.x);
        ay += w * (vf.y + a * we4.y);
        az += w * (vf.z + a * we4.z);
        aw += w * (vf.w + a * we4.w);
    }
    const float inv = 1.f / (ssum + 1e-16f);
    const float4 sk = *(const float4*)(out + (size_t)n * 256 + lane * 4);
    float4 o;
    o.x = ax * inv + sk.x;
    o.y = ay * inv + sk.y;
    o.z = az * inv + sk.z;
    o.w = aw * inv + sk.w;
    *(float4*)(out + (size_t)n * 256 + lane * 4) = o;
}

// ---------------- GraphNorm ----------------
__global__ __launch_bounds__(256) void gn_stats_k(const float* __restrict__ out,
                                                  float* __restrict__ gstats)
{
    const int c = threadIdx.x;
    float s = 0.f, s2 = 0.f;
    for (int r = blockIdx.x; r < N_NODES; r += gridDim.x) {
        const float vv = out[(size_t)r * 256 + c];
        s += vv; s2 += vv * vv;
    }
    atomicAdd(&gstats[c], s);
    atomicAdd(&gstats[256 + c], s2);
}

__global__ __launch_bounds__(256) void norm_relu_k(float* __restrict__ out,
                                                   const float* __restrict__ gstats,
                                                   const float* __restrict__ gw,
                                                   const float* __restrict__ gb,
                                                   const float* __restrict__ gms)
{
    const int c = threadIdx.x;
    const float invN = 1.f / (float)N_NODES;
    const float mean = gstats[c] * invN;
    const float exx  = gstats[256 + c] * invN;
    const float mu   = gms[c] * mean;
    const float var  = exx - 2.f * mu * mean + mu * mu;
    const float winv = gw[c] * rsqrtf(var + 1e-5f);
    const float badd = gb[c];
    for (int r = blockIdx.x; r < N_NODES; r += gridDim.x) {
        const float vv = out[(size_t)r * 256 + c];
        const float t  = (vv - mu) * winv + badd;
        out[(size_t)r * 256 + c] = fmaxf(t, 0.f);
    }
}

// ---------------- Gram: xt = A^T A (split-K, atomic accumulate) ----------------
__global__ __launch_bounds__(256) void gram_k(const float* __restrict__ A,
                                              float* __restrict__ xt)
{
    const int bi = blockIdx.x, bj = blockIdx.y;
    const int chunk = (N_NODES + gridDim.z - 1) / gridDim.z;
    const int r0 = blockIdx.z * chunk;
    const int r1 = min(N_NODES, r0 + chunk);
    __shared__ float Ai[16][68];
    __shared__ float Aj[16][68];
    const int tid = threadIdx.x;
    const int ti = (tid >> 4) * 4, tj = (tid & 15) * 4;
    const int lr = tid >> 4, lc = (tid & 15) * 4;
    float acc[4][4] = {};
    for (int r = r0; r < r1; r += 16) {
        float4 av = make_float4(0.f, 0.f, 0.f, 0.f);
        float4 bv = av;
        const int gr = r + lr;
        if (gr < r1) {
            av = *(const float4*)(A + (size_t)gr * 256 + bi * 64 + lc);
            bv = *(const float4*)(A + (size_t)gr * 256 + bj * 64 + lc);
        }
        __syncthreads();
        *(float4*)&Ai[lr][lc] = av;
        *(float4*)&Aj[lr][lc] = bv;
        __syncthreads();
#pragma unroll
        for (int kk = 0; kk < 16; ++kk) {
            const float4 a = *(const float4*)&Ai[kk][ti];
            const float4 b = *(const float4*)&Aj[kk][tj];
            const float aa[4] = {a.x, a.y, a.z, a.w};
            const float bb[4] = {b.x, b.y, b.z, b.w};
#pragma unroll
            for (int i = 0; i < 4; ++i)
#pragma unroll
                for (int j = 0; j < 4; ++j)
                    acc[i][j] += aa[i] * bb[j];
        }
    }
#pragma unroll
    for (int i = 0; i < 4; ++i)
#pragma unroll
        for (int j = 0; j < 4; ++j)
            atomicAdd(&xt[(size_t)(bi * 64 + ti + i) * 256 + bj * 64 + tj + j], acc[i][j]);
}

// ---------------- min/max + final normalize ----------------
__global__ __launch_bounds__(1024) void minmax_k(const float* __restrict__ xt,
                                                 float* __restrict__ mm)
{
    const int tid = threadIdx.x;
    float mn = 1e30f, mx = -1e30f;
    for (int i = tid; i < 65536; i += 1024) {
        const float v = xt[i];
        mn = fminf(mn, v);
        mx = fmaxf(mx, v);
    }
    for (int off = 1; off < 64; off <<= 1) {
        mn = fminf(mn, __shfl_xor(mn, off));
        mx = fmaxf(mx, __shfl_xor(mx, off));
    }
    __shared__ float smn[16], smx[16];
    const int w = tid >> 6;
    if ((tid & 63) == 0) { smn[w] = mn; smx[w] = mx; }
    __syncthreads();
    if (tid == 0) {
        for (int i = 1; i < 16; ++i) {
            mn = fminf(mn, smn[i]);
            mx = fmaxf(mx, smx[i]);
        }
        mm[0] = mn; mm[1] = mx;
    }
}

__global__ void finalize_k(const float* __restrict__ xt, const float* __restrict__ mm,
                           float* __restrict__ outp)
{
    const int i = blockIdx.x * 256 + threadIdx.x;
    const float mn = mm[0], mx = mm[1];
    const float inv = 1.f / (mx - mn + 1e-8f);
    outp[i] = (xt[i] - mn) * inv;
}

// ---------------- launch ----------------
extern "C" void kernel_launch(void* const* d_in, const int* in_sizes, int n_in,
                              void* d_out, int out_size, void* d_ws, size_t ws_size,
                              hipStream_t stream)
{
    (void)in_sizes; (void)n_in; (void)out_size; (void)ws_size;
    const float* x   = (const float*)d_in[0];
    const int*   ei  = (const int*)d_in[1];
    const float* ea  = (const float*)d_in[2];
    const float* Wq  = (const float*)d_in[3];
    const float* bq  = (const float*)d_in[4];
    const float* Wk  = (const float*)d_in[5];
    const float* bk  = (const float*)d_in[6];
    const float* Wv  = (const float*)d_in[7];
    const float* bv  = (const float*)d_in[8];
    const float* We  = (const float*)d_in[9];
    const float* Wsk = (const float*)d_in[10];
    const float* bsk = (const float*)d_in[11];
    const float* gw  = (const float*)d_in[12];
    const float* gb  = (const float*)d_in[13];
    const float* gms = (const float*)d_in[14];
    float* outp = (float*)d_out;

    char* ws = (char*)d_ws;
    size_t off = 0;
    float* qb = (float*)(ws + off); off += (size_t)N_NODES * 256 * 4;
    float* kb = (float*)(ws + off); off += (size_t)N_NODES * 256 * 4;
    float* vb = (float*)(ws + off); off += (size_t)N_NODES * 256 * 4;
    float* ob = (float*)(ws + off); off += (size_t)N_NODES * 256 * 4;   // skip -> out (in place)
    float* ab = (float*)(ws + off); off += (size_t)N_EDGES * 4 * 4;     // alpha[E,4]
    // ---- zero region (reset every call; graph replays the memset) ----
    const size_t zoff = off;
    int*   deg    = (int*)(ws + off);   off += (size_t)N_NODES * 4;
    int*   cur    = (int*)(ws + off);   off += (size_t)N_NODES * 4;
    float* gstats = (float*)(ws + off); off += 512 * 4;
    float* xt     = (float*)(ws + off); off += 65536 * 4;
    const size_t zbytes = off - zoff;
    // ---- end zero region ----
    int* row_start = (int*)(ws + off);  off += (size_t)(N_NODES + 1) * 4;
    int* edge_ids  = (int*)(ws + off);  off += (size_t)N_EDGES * 4;
    float* mm      = (float*)(ws + off); off += 2 * 4;

    const int* srcv = ei;            // edge_index[0]
    const int* dstv = ei + N_EDGES;  // edge_index[1]

    hipMemsetAsync(ws + zoff, 0, zbytes, stream);

    const dim3 gg((N_NODES + 63) / 64, 4);
    gemm256<<<gg, 256, 0, stream>>>(x, Wq,  bq,  qb, N_NODES);
    gemm256<<<gg, 256, 0, stream>>>(x, Wk,  bk,  kb, N_NODES);
    gemm256<<<gg, 256, 0, stream>>>(x, Wv,  bv,  vb, N_NODES);
    gemm256<<<gg, 256, 0, stream>>>(x, Wsk, bsk, ob, N_NODES);

    count_deg<<<(N_EDGES + 255) / 256, 256, 0, stream>>>(dstv, deg);
    scan_k<<<1, 1024, 0, stream>>>(deg, row_start);
    fill_csr<<<(N_EDGES + 255) / 256, 256, 0, stream>>>(dstv, row_start, cur, edge_ids);

    attn_k<<<(N_NODES + 3) / 4, 256, 0, stream>>>(qb, kb, vb, ea, We, srcv,
                                                  row_start, edge_ids, ab, ob);

    gn_stats_k<<<160, 256, 0, stream>>>(ob, gstats);
    norm_relu_k<<<256, 256, 0, stream>>>(ob, gstats, gw, gb, gms);

    gram_k<<<dim3(4, 4, 64), 256, 0, stream>>>(ob, xt);
    minmax_k<<<1, 1024, 0, stream>>>(xt, mm);
    finalize_k<<<256, 256, 0, stream>>>(xt, mm, outp);
}

// Round 2
// 356.829 us; speedup vs baseline: 1.4901x; 1.4901x over previous
//
#include <hip/hip_runtime.h>
#include <math.h>

#define N_NODES 20000
#define N_EDGES 320000

typedef short short8 __attribute__((ext_vector_type(8)));
typedef float f32x4 __attribute__((ext_vector_type(4)));

static __device__ __forceinline__ unsigned short f2bf(float f) {
    unsigned int u = __float_as_uint(f);
    u = (u + 0x7FFF + ((u >> 16) & 1)) >> 16;
    return (unsigned short)u;
}
static __device__ __forceinline__ float b2f(unsigned short u) {
    return __uint_as_float((unsigned int)u << 16);
}

// ---------------- convert x -> bf16 ----------------
__global__ __launch_bounds__(256) void conv_x_k(const float* __restrict__ x,
                                                unsigned short* __restrict__ xb)
{
    const int t8 = blockIdx.x * 256 + threadIdx.x;
    const size_t base = (size_t)t8 * 8;
    if (base >= (size_t)N_NODES * 256) return;
    const float4 f0 = *(const float4*)(x + base);
    const float4 f1 = *(const float4*)(x + base + 4);
    ushort4 u0, u1;
    u0.x = f2bf(f0.x); u0.y = f2bf(f0.y); u0.z = f2bf(f0.z); u0.w = f2bf(f0.w);
    u1.x = f2bf(f1.x); u1.y = f2bf(f1.y); u1.z = f2bf(f1.z); u1.w = f2bf(f1.w);
    *(ushort4*)(xb + base) = u0;
    *(ushort4*)(xb + base + 4) = u1;
}

// ---------------- build wT bf16 [1024][256] (= W^T per matrix) + bias_all ----------------
__global__ __launch_bounds__(256) void conv_w_k(const float* __restrict__ Wq,
                                                const float* __restrict__ Wk,
                                                const float* __restrict__ Wv,
                                                const float* __restrict__ Wsk,
                                                const float* __restrict__ bq,
                                                const float* __restrict__ bk,
                                                const float* __restrict__ bv,
                                                const float* __restrict__ bsk,
                                                unsigned short* __restrict__ wT,
                                                float* __restrict__ bias_all)
{
    const int b = blockIdx.x;          // 0..1023 : wi*256 + n
    const int kk = threadIdx.x;        // 0..255
    const int wi = b >> 8, n = b & 255;
    const float* W = (wi == 0) ? Wq : (wi == 1) ? Wk : (wi == 2) ? Wv : Wsk;
    wT[(size_t)b * 256 + kk] = f2bf(W[(size_t)kk * 256 + n]);
    if (kk == 0) {
        const float* bb = (wi == 0) ? bq : (wi == 1) ? bk : (wi == 2) ? bv : bsk;
        bias_all[b] = bb[n];
    }
}

// ---------------- fused QKVS GEMM (bf16 MFMA): [20000,256] @ [256,1024] ----------------
__global__ __launch_bounds__(256) void gemm_qkvs(const unsigned short* __restrict__ xb,
                                                 const unsigned short* __restrict__ wT,
                                                 const float* __restrict__ bias_all,
                                                 float* __restrict__ qb,
                                                 unsigned short* __restrict__ kb,
                                                 unsigned short* __restrict__ vb,
                                                 float* __restrict__ ob)
{
    __shared__ __align__(16) unsigned short As[128 * 80];
    __shared__ __align__(16) unsigned short Bs[64 * 80];
    const int tid = threadIdx.x;
    const int lane = tid & 63;
    const int w = tid >> 6;
    const int wm = w >> 1, wn = w & 1;
    const int row0 = blockIdx.x * 128;
    const int col0 = blockIdx.y * 64;      // 0..960, global col in [0,1024)
    const int lr = tid >> 3;               // 0..31
    const int seg = (tid & 7) * 8;         // 0,8,..,56
    const int fr = lane & 15;              // frag row/col select
    const int fk = (lane >> 4) * 8;        // frag k offset

    f32x4 acc[4][2] = {};

    for (int k0 = 0; k0 < 256; k0 += 64) {
        float4 a_ld[4], b_ld[2];
#pragma unroll
        for (int p = 0; p < 4; ++p) {
            int gr = row0 + lr + 32 * p;
            gr = gr < N_NODES - 1 ? gr : N_NODES - 1;     // clamp tail (stores guarded)
            a_ld[p] = *(const float4*)(xb + (size_t)gr * 256 + k0 + seg);
        }
#pragma unroll
        for (int p = 0; p < 2; ++p)
            b_ld[p] = *(const float4*)(wT + (size_t)(col0 + lr + 32 * p) * 256 + k0 + seg);
        __syncthreads();
#pragma unroll
        for (int p = 0; p < 4; ++p)
            *(float4*)&As[(lr + 32 * p) * 80 + seg] = a_ld[p];
#pragma unroll
        for (int p = 0; p < 2; ++p)
            *(float4*)&Bs[(lr + 32 * p) * 80 + seg] = b_ld[p];
        __syncthreads();
#pragma unroll
        for (int ks = 0; ks < 2; ++ks) {
            short8 af[4], bf[2];
#pragma unroll
            for (int m = 0; m < 4; ++m)
                af[m] = *(const short8*)&As[(wm * 64 + m * 16 + fr) * 80 + ks * 32 + fk];
#pragma unroll
            for (int n = 0; n < 2; ++n)
                bf[n] = *(const short8*)&Bs[(wn * 32 + n * 16 + fr) * 80 + ks * 32 + fk];
#pragma unroll
            for (int m = 0; m < 4; ++m)
#pragma unroll
                for (int n = 0; n < 2; ++n)
                    acc[m][n] = __builtin_amdgcn_mfma_f32_16x16x32_bf16(af[m], bf[n], acc[m][n], 0, 0, 0);
        }
    }

    const int buf = col0 >> 8;             // 0=q 1=k 2=v 3=skip (uniform per block)
#pragma unroll
    for (int n = 0; n < 2; ++n) {
        const int gcol = col0 + wn * 32 + n * 16 + fr;
        const float badd = bias_all[gcol];
        const int col = gcol & 255;
#pragma unroll
        for (int m = 0; m < 4; ++m) {
#pragma unroll
            for (int r = 0; r < 4; ++r) {
                const int grow = row0 + wm * 64 + m * 16 + (lane >> 4) * 4 + r;
                if (grow < N_NODES) {
                    const float val = acc[m][n][r] + badd;
                    const size_t idx = (size_t)grow * 256 + col;
                    if (buf == 0)       qb[idx] = val;
                    else if (buf == 1)  kb[idx] = f2bf(val);
                    else if (buf == 2)  vb[idx] = f2bf(val);
                    else                ob[idx] = val;
                }
            }
        }
    }
}

// ---------------- CSR build ----------------
__global__ void count_deg(const int* __restrict__ dst, int* __restrict__ deg)
{
    const int e = blockIdx.x * 256 + threadIdx.x;
    if (e < N_EDGES) atomicAdd(&deg[dst[e]], 1);
}

__global__ __launch_bounds__(1024) void scan_k(const int* __restrict__ deg,
                                               int* __restrict__ row_start)
{
    const int tid = threadIdx.x;
    const int lane = tid & 63, wid = tid >> 6;
    const int CH = 20;                       // 1024*20 = 20480 >= 20000
    const int base = tid * CH;
    int local[CH];
    int s = 0;
#pragma unroll
    for (int i = 0; i < CH; ++i) {
        const int idx = base + i;
        const int d = (idx < N_NODES) ? deg[idx] : 0;
        local[i] = s;
        s += d;
    }
    // inclusive scan of s across the wave
    int v = s;
#pragma unroll
    for (int off = 1; off < 64; off <<= 1) {
        const int t = __shfl_up(v, off);
        if (lane >= off) v += t;
    }
    __shared__ int wsum[16];
    if (lane == 63) wsum[wid] = v;
    __syncthreads();
    if (tid == 0) {
        int r = 0;
        for (int i = 0; i < 16; ++i) { const int t = wsum[i]; wsum[i] = r; r += t; }
    }
    __syncthreads();
    const int excl = v - s + wsum[wid];      // exclusive prefix for this thread's chunk
#pragma unroll
    for (int i = 0; i < CH; ++i) {
        const int idx = base + i;
        if (idx < N_NODES) row_start[idx] = excl + local[i];
    }
    if (tid == 1023) row_start[N_NODES] = excl + s;
}

__global__ void fill_csr(const int* __restrict__ dst, const int* __restrict__ row_start,
                         int* __restrict__ cursor, int* __restrict__ edge_ids)
{
    const int e = blockIdx.x * 256 + threadIdx.x;
    if (e < N_EDGES) {
        const int d = dst[e];
        const int p = atomicAdd(&cursor[d], 1);
        edge_ids[row_start[d] + p] = e;
    }
}

// ---------------- attention: single pass, bf16 k/v gather ----------------
__global__ __launch_bounds__(256) void attn_k(const float* __restrict__ q,
                                              const unsigned short* __restrict__ kb,
                                              const unsigned short* __restrict__ vb,
                                              const float* __restrict__ ea,
                                              const float* __restrict__ We,
                                              const int* __restrict__ src,
                                              const int* __restrict__ row_start,
                                              const int* __restrict__ edge_ids,
                                              float* __restrict__ out)
{
    const int wid  = threadIdx.x >> 6;
    const int lane = threadIdx.x & 63;
    const int n = blockIdx.x * 4 + wid;
    if (n >= N_NODES) return;

    const float4 qf  = *(const float4*)(q + (size_t)n * 256 + lane * 4);
    const float4 we4 = *(const float4*)(We + lane * 4);
    const int rs = row_start[n], re = row_start[n + 1];

    float ssum = 0.f;
    float ax = 0.f, ay = 0.f, az = 0.f, aw = 0.f;

    int sn = 0; float a = 0.f;
    if (rs < re) { const int e = edge_ids[rs]; sn = src[e]; a = ea[e]; }
    for (int s = rs; s < re; ++s) {
        const int   sn_c = sn;
        const float a_c  = a;
        const ushort4 k4 = *(const ushort4*)(kb + (size_t)sn_c * 256 + lane * 4);
        const ushort4 v4 = *(const ushort4*)(vb + (size_t)sn_c * 256 + lane * 4);
        if (s + 1 < re) { const int e2 = edge_ids[s + 1]; sn = src[e2]; a = ea[e2]; }

        float p = qf.x * (b2f(k4.x) + a_c * we4.x)
                + qf.y * (b2f(k4.y) + a_c * we4.y)
                + qf.z * (b2f(k4.z) + a_c * we4.z)
                + qf.w * (b2f(k4.w) + a_c * we4.w);
        p += __shfl_xor(p, 1);
        p += __shfl_xor(p, 2);
        p += __shfl_xor(p, 4);
        p += __shfl_xor(p, 8);
        p *= 0.125f;                        // 1/sqrt(64)
        const float wgt = __expf(p);        // logits tiny; max-shift is redundant
        ssum += wgt;
        ax += wgt * (b2f(v4.x) + a_c * we4.x);
        ay += wgt * (b2f(v4.y) + a_c * we4.y);
        az += wgt * (b2f(v4.z) + a_c * we4.z);
        aw += wgt * (b2f(v4.w) + a_c * we4.w);
    }
    const float inv = 1.f / (ssum + 1e-16f);
    const float4 sk = *(const float4*)(out + (size_t)n * 256 + lane * 4);
    float4 o;
    o.x = ax * inv + sk.x;
    o.y = ay * inv + sk.y;
    o.z = az * inv + sk.z;
    o.w = aw * inv + sk.w;
    *(float4*)(out + (size_t)n * 256 + lane * 4) = o;
}

// ---------------- GraphNorm ----------------
__global__ __launch_bounds__(256) void gn_stats_k(const float* __restrict__ out,
                                                  float* __restrict__ gstats)
{
    const int c = threadIdx.x;
    float s = 0.f, s2 = 0.f;
    for (int r = blockIdx.x; r < N_NODES; r += gridDim.x) {
        const float vv = out[(size_t)r * 256 + c];
        s += vv; s2 += vv * vv;
    }
    atomicAdd(&gstats[c], s);
    atomicAdd(&gstats[256 + c], s2);
}

__global__ __launch_bounds__(256) void norm_relu_k(float* __restrict__ out,
                                                   const float* __restrict__ gstats,
                                                   const float* __restrict__ gw,
                                                   const float* __restrict__ gb,
                                                   const float* __restrict__ gms)
{
    const int c = threadIdx.x;
    const float invN = 1.f / (float)N_NODES;
    const float mean = gstats[c] * invN;
    const float exx  = gstats[256 + c] * invN;
    const float mu   = gms[c] * mean;
    const float var  = exx - 2.f * mu * mean + mu * mu;
    const float winv = gw[c] * rsqrtf(var + 1e-5f);
    const float badd = gb[c];
    for (int r = blockIdx.x; r < N_NODES; r += gridDim.x) {
        const float vv = out[(size_t)r * 256 + c];
        const float t  = (vv - mu) * winv + badd;
        out[(size_t)r * 256 + c] = fmaxf(t, 0.f);
    }
}

// ---------------- Gram: xt = A^T A, upper-triangle block pairs only ----------------
__global__ __launch_bounds__(256) void gram_k(const float* __restrict__ A,
                                              float* __restrict__ xt)
{
    const int bi_l[10] = {0,0,0,0,1,1,1,2,2,3};
    const int bj_l[10] = {0,1,2,3,1,2,3,2,3,3};
    const int bi = bi_l[blockIdx.x], bj = bj_l[blockIdx.x];
    const int chunk = (N_NODES + gridDim.z - 1) / gridDim.z;
    const int r0 = blockIdx.z * chunk;
    const int r1 = min(N_NODES, r0 + chunk);
    __shared__ float Ai[16][68];
    __shared__ float Aj[16][68];
    const int tid = threadIdx.x;
    const int ti = (tid >> 4) * 4, tj = (tid & 15) * 4;
    const int lr = tid >> 4, lc = (tid & 15) * 4;
    float acc[4][4] = {};
    for (int r = r0; r < r1; r += 16) {
        float4 av = make_float4(0.f, 0.f, 0.f, 0.f);
        float4 bv = av;
        const int gr = r + lr;
        if (gr < r1) {
            av = *(const float4*)(A + (size_t)gr * 256 + bi * 64 + lc);
            bv = *(const float4*)(A + (size_t)gr * 256 + bj * 64 + lc);
        }
        __syncthreads();
        *(float4*)&Ai[lr][lc] = av;
        *(float4*)&Aj[lr][lc] = bv;
        __syncthreads();
#pragma unroll
        for (int kk = 0; kk < 16; ++kk) {
            const float4 a = *(const float4*)&Ai[kk][ti];
            const float4 b = *(const float4*)&Aj[kk][tj];
            const float aa[4] = {a.x, a.y, a.z, a.w};
            const float bb[4] = {b.x, b.y, b.z, b.w};
#pragma unroll
            for (int i = 0; i < 4; ++i)
#pragma unroll
                for (int j = 0; j < 4; ++j)
                    acc[i][j] += aa[i] * bb[j];
        }
    }
#pragma unroll
    for (int i = 0; i < 4; ++i)
#pragma unroll
        for (int j = 0; j < 4; ++j)
            atomicAdd(&xt[(size_t)(bi * 64 + ti + i) * 256 + bj * 64 + tj + j], acc[i][j]);
}

// ---------------- min/max over valid (upper) blocks + final normalize w/ mirror ----------------
__global__ __launch_bounds__(1024) void minmax_k(const float* __restrict__ xt,
                                                 float* __restrict__ mm)
{
    const int tid = threadIdx.x;
    float mn = 1e30f, mx = -1e30f;
    for (int i = tid; i < 65536; i += 1024) {
        const int r = i >> 8, c = i & 255;
        if ((r >> 6) <= (c >> 6)) {
            const float v = xt[i];
            mn = fminf(mn, v);
            mx = fmaxf(mx, v);
        }
    }
    for (int off = 1; off < 64; off <<= 1) {
        mn = fminf(mn, __shfl_xor(mn, off));
        mx = fmaxf(mx, __shfl_xor(mx, off));
    }
    __shared__ float smn[16], smx[16];
    const int w = tid >> 6;
    if ((tid & 63) == 0) { smn[w] = mn; smx[w] = mx; }
    __syncthreads();
    if (tid == 0) {
        for (int i = 1; i < 16; ++i) {
            mn = fminf(mn, smn[i]);
            mx = fmaxf(mx, smx[i]);
        }
        mm[0] = mn; mm[1] = mx;
    }
}

__global__ void finalize_k(const float* __restrict__ xt, const float* __restrict__ mm,
                           float* __restrict__ outp)
{
    const int i = blockIdx.x * 256 + threadIdx.x;
    const int r = i >> 8, c = i & 255;
    const float v = ((r >> 6) <= (c >> 6)) ? xt[i] : xt[c * 256 + r];
    const float mn = mm[0], mx = mm[1];
    const float inv = 1.f / (mx - mn + 1e-8f);
    outp[i] = (v - mn) * inv;
}

// ---------------- launch ----------------
extern "C" void kernel_launch(void* const* d_in, const int* in_sizes, int n_in,
                              void* d_out, int out_size, void* d_ws, size_t ws_size,
                              hipStream_t stream)
{
    (void)in_sizes; (void)n_in; (void)out_size; (void)ws_size;
    const float* x   = (const float*)d_in[0];
    const int*   ei  = (const int*)d_in[1];
    const float* ea  = (const float*)d_in[2];
    const float* Wq  = (const float*)d_in[3];
    const float* bq  = (const float*)d_in[4];
    const float* Wk  = (const float*)d_in[5];
    const float* bk  = (const float*)d_in[6];
    const float* Wv  = (const float*)d_in[7];
    const float* bv  = (const float*)d_in[8];
    const float* We  = (const float*)d_in[9];
    const float* Wsk = (const float*)d_in[10];
    const float* bsk = (const float*)d_in[11];
    const float* gw  = (const float*)d_in[12];
    const float* gb  = (const float*)d_in[13];
    const float* gms = (const float*)d_in[14];
    float* outp = (float*)d_out;

    char* ws = (char*)d_ws;
    size_t off = 0;
    unsigned short* xb = (unsigned short*)(ws + off); off += (size_t)N_NODES * 256 * 2;
    unsigned short* wT = (unsigned short*)(ws + off); off += (size_t)1024 * 256 * 2;
    float* bias_all    = (float*)(ws + off);          off += 1024 * 4;
    float* qb = (float*)(ws + off);          off += (size_t)N_NODES * 256 * 4;
    unsigned short* kb = (unsigned short*)(ws + off); off += (size_t)N_NODES * 256 * 2;
    unsigned short* vb = (unsigned short*)(ws + off); off += (size_t)N_NODES * 256 * 2;
    float* ob = (float*)(ws + off);          off += (size_t)N_NODES * 256 * 4;
    // ---- zero region (reset every call) ----
    const size_t zoff = off;
    int*   deg    = (int*)(ws + off);   off += (size_t)N_NODES * 4;
    int*   cur    = (int*)(ws + off);   off += (size_t)N_NODES * 4;
    float* gstats = (float*)(ws + off); off += 512 * 4;
    float* xt     = (float*)(ws + off); off += 65536 * 4;
    const size_t zbytes = off - zoff;
    // ---- end zero region ----
    int* row_start = (int*)(ws + off);  off += (size_t)(N_NODES + 1) * 4;
    int* edge_ids  = (int*)(ws + off);  off += (size_t)N_EDGES * 4;
    float* mm      = (float*)(ws + off); off += 2 * 4;

    const int* srcv = ei;            // edge_index[0]
    const int* dstv = ei + N_EDGES;  // edge_index[1]

    hipMemsetAsync(ws + zoff, 0, zbytes, stream);

    conv_x_k<<<(N_NODES * 256 / 8 + 255) / 256, 256, 0, stream>>>(x, xb);
    conv_w_k<<<1024, 256, 0, stream>>>(Wq, Wk, Wv, Wsk, bq, bk, bv, bsk, wT, bias_all);

    gemm_qkvs<<<dim3((N_NODES + 127) / 128, 16), 256, 0, stream>>>(xb, wT, bias_all,
                                                                   qb, kb, vb, ob);

    count_deg<<<(N_EDGES + 255) / 256, 256, 0, stream>>>(dstv, deg);
    scan_k<<<1, 1024, 0, stream>>>(deg, row_start);
    fill_csr<<<(N_EDGES + 255) / 256, 256, 0, stream>>>(dstv, row_start, cur, edge_ids);

    attn_k<<<(N_NODES + 3) / 4, 256, 0, stream>>>(qb, kb, vb, ea, We, srcv,
                                                  row_start, edge_ids, ob);

    gn_stats_k<<<160, 256, 0, stream>>>(ob, gstats);
    norm_relu_k<<<256, 256, 0, stream>>>(ob, gstats, gw, gb, gms);

    gram_k<<<dim3(10, 1, 64), 256, 0, stream>>>(ob, xt);
    minmax_k<<<1, 1024, 0, stream>>>(xt, mm);
    finalize_k<<<256, 256, 0, stream>>>(xt, mm, outp);
}

// Round 7
// 235.456 us; speedup vs baseline: 2.2582x; 1.5155x over previous
//
#include <hip/hip_runtime.h>
#include <math.h>

#define N_NODES 20000
#define N_EDGES 320000
#define SK 20480   // zero-padded K (rows) for transposed gram operand

typedef short short8 __attribute__((ext_vector_type(8)));
typedef float f32x4 __attribute__((ext_vector_type(4)));

static __device__ __forceinline__ unsigned short f2bf(float f) {
    unsigned int u = __float_as_uint(f);
    u = (u + 0x7FFF + ((u >> 16) & 1)) >> 16;
    return (unsigned short)u;
}
static __device__ __forceinline__ float b2f(unsigned short u) {
    return __uint_as_float((unsigned int)u << 16);
}

// ---------------- convert x -> bf16 ----------------
__global__ __launch_bounds__(256) void conv_x_k(const float* __restrict__ x,
                                                unsigned short* __restrict__ xb)
{
    const int t8 = blockIdx.x * 256 + threadIdx.x;
    const size_t base = (size_t)t8 * 8;
    if (base >= (size_t)N_NODES * 256) return;
    const float4 f0 = *(const float4*)(x + base);
    const float4 f1 = *(const float4*)(x + base + 4);
    ushort4 u0, u1;
    u0.x = f2bf(f0.x); u0.y = f2bf(f0.y); u0.z = f2bf(f0.z); u0.w = f2bf(f0.w);
    u1.x = f2bf(f1.x); u1.y = f2bf(f1.y); u1.z = f2bf(f1.z); u1.w = f2bf(f1.w);
    *(ushort4*)(xb + base) = u0;
    *(ushort4*)(xb + base + 4) = u1;
}

// ---------------- build wT bf16 [1024][256] + bias_all ----------------
__global__ __launch_bounds__(256) void conv_w_k(const float* __restrict__ Wq,
                                                const float* __restrict__ Wk,
                                                const float* __restrict__ Wv,
                                                const float* __restrict__ Wsk,
                                                const float* __restrict__ bq,
                                                const float* __restrict__ bk,
                                                const float* __restrict__ bv,
                                                const float* __restrict__ bsk,
                                                unsigned short* __restrict__ wT,
                                                float* __restrict__ bias_all)
{
    const int b = blockIdx.x;          // 0..1023 : wi*256 + n
    const int kk = threadIdx.x;        // 0..255
    const int wi = b >> 8, n = b & 255;
    const float* W = (wi == 0) ? Wq : (wi == 1) ? Wk : (wi == 2) ? Wv : Wsk;
    wT[(size_t)b * 256 + kk] = f2bf(W[(size_t)kk * 256 + n]);
    if (kk == 0) {
        const float* bb = (wi == 0) ? bq : (wi == 1) ? bk : (wi == 2) ? bv : bsk;
        bias_all[b] = bb[n];
    }
}

// ---------------- fused QKVS GEMM: tile 128x256, LDS-staged coalesced epilogue ----------------
// (round-3 structure with the ushort4->uint4 load-width fix: uint4 = 16B = 8 bf16)
__global__ __launch_bounds__(512, 2) void gemm_qkvs(const unsigned short* __restrict__ xb,
                                                    const unsigned short* __restrict__ wT,
                                                    const float* __restrict__ bias_all,
                                                    float* __restrict__ qb,
                                                    unsigned short* __restrict__ kb,
                                                    unsigned short* __restrict__ vb,
                                                    float* __restrict__ ob)
{
    __shared__ __align__(16) unsigned short As[(128 + 256) * 80];   // As(128x80) then Bs(256x80)
    unsigned short* Bs = As + 128 * 80;
    float* stage = (float*)As;                                      // reused after K-loop

    const int tid  = threadIdx.x;
    const int lane = tid & 63;
    const int w    = tid >> 6;         // 0..7
    const int wm = w >> 2, wn = w & 3; // wave grid 2x4 (64-row x 64-col per wave)
    const int row0 = blockIdx.x * 128;
    const int wsel = blockIdx.y;       // 0=q 1=k 2=v 3=skip
    const int colG = wsel * 256;
    const int ar = tid >> 2, ak = (tid & 3) * 16;   // A: 128 rows x 16 k-elems
    const int br = tid >> 1, bk = (tid & 1) * 32;   // B: 256 rows x 32 k-elems
    const int fr = lane & 15, fk = (lane >> 4) * 8, lg = lane >> 4;

    f32x4 acc[4][4] = {};

    for (int k0 = 0; k0 < 256; k0 += 64) {
        int gr = row0 + ar; gr = gr < N_NODES ? gr : N_NODES - 1;
        const unsigned short* ap = xb + (size_t)gr * 256 + k0 + ak;
        const uint4 a0 = *(const uint4*)ap;          // elems [0..7]
        const uint4 a1 = *(const uint4*)(ap + 8);    // elems [8..15]
        const unsigned short* bp = wT + (size_t)(colG + br) * 256 + k0 + bk;
        const uint4 b0 = *(const uint4*)bp;          // [0..7]
        const uint4 b1 = *(const uint4*)(bp + 8);    // [8..15]
        const uint4 b2 = *(const uint4*)(bp + 16);   // [16..23]
        const uint4 b3 = *(const uint4*)(bp + 24);   // [24..31]
        __syncthreads();
        *(uint4*)&As[ar * 80 + ak]     = a0;
        *(uint4*)&As[ar * 80 + ak + 8] = a1;
        unsigned short* bsp = &Bs[br * 80 + bk];
        *(uint4*)bsp        = b0;
        *(uint4*)(bsp + 8)  = b1;
        *(uint4*)(bsp + 16) = b2;
        *(uint4*)(bsp + 24) = b3;
        __syncthreads();
#pragma unroll
        for (int ks = 0; ks < 2; ++ks) {
            short8 af[4], bf[4];
#pragma unroll
            for (int m = 0; m < 4; ++m)
                af[m] = *(const short8*)&As[(wm * 64 + m * 16 + fr) * 80 + ks * 32 + fk];
#pragma unroll
            for (int n = 0; n < 4; ++n)
                bf[n] = *(const short8*)&Bs[(wn * 64 + n * 16 + fr) * 80 + ks * 32 + fk];
#pragma unroll
            for (int m = 0; m < 4; ++m)
#pragma unroll
                for (int n = 0; n < 4; ++n)
                    acc[m][n] = __builtin_amdgcn_mfma_f32_16x16x32_bf16(af[m], bf[n], acc[m][n], 0, 0, 0);
        }
    }
    __syncthreads();                   // all frag reads done; LDS reusable

    float badd[4];
#pragma unroll
    for (int n = 0; n < 4; ++n) badd[n] = bias_all[colG + wn * 64 + n * 16 + fr];

    float* st = stage + w * 1024;      // 4 KB wave-private staging (16 rows x 64 cols)
#pragma unroll
    for (int m = 0; m < 4; ++m) {
#pragma unroll
        for (int n = 0; n < 4; ++n)
#pragma unroll
            for (int r = 0; r < 4; ++r)
                st[(lg * 4 + r) * 64 + n * 16 + fr] = acc[m][n][r] + badd[n];
#pragma unroll
        for (int it = 0; it < 4; ++it) {
            const int lrow = it * 4 + lg;
            const f32x4 c4 = *(const f32x4*)&st[lrow * 64 + fr * 4];
            const int grow = row0 + wm * 64 + m * 16 + lrow;
            if (grow < N_NODES) {
                const size_t idx = (size_t)grow * 256 + wn * 64 + fr * 4;
                if (wsel == 0) {
                    float4 o; o.x = c4[0]; o.y = c4[1]; o.z = c4[2]; o.w = c4[3];
                    *(float4*)(qb + idx) = o;
                } else if (wsel == 3) {
                    float4 o; o.x = c4[0]; o.y = c4[1]; o.z = c4[2]; o.w = c4[3];
                    *(float4*)(ob + idx) = o;
                } else {
                    ushort4 u;
                    u.x = f2bf(c4[0]); u.y = f2bf(c4[1]); u.z = f2bf(c4[2]); u.w = f2bf(c4[3]);
                    if (wsel == 1) *(ushort4*)(kb + idx) = u;
                    else           *(ushort4*)(vb + idx) = u;
                }
            }
        }
    }
}

// ---------------- CSR build ----------------
__global__ void count_deg(const int* __restrict__ dst, int* __restrict__ deg)
{
    const int e = blockIdx.x * 256 + threadIdx.x;
    if (e < N_EDGES) atomicAdd(&deg[dst[e]], 1);
}

__global__ __launch_bounds__(1024) void scan_k(const int* __restrict__ deg,
                                               int* __restrict__ row_start)
{
    const int tid = threadIdx.x;
    const int lane = tid & 63, wid = tid >> 6;
    const int CH = 20;
    const int base = tid * CH;
    int local[CH];
    int s = 0;
#pragma unroll
    for (int i = 0; i < CH; ++i) {
        const int idx = base + i;
        const int d = (idx < N_NODES) ? deg[idx] : 0;
        local[i] = s;
        s += d;
    }
    int v = s;
#pragma unroll
    for (int off = 1; off < 64; off <<= 1) {
        const int t = __shfl_up(v, off);
        if (lane >= off) v += t;
    }
    __shared__ int wsum[16];
    if (lane == 63) wsum[wid] = v;
    __syncthreads();
    if (tid == 0) {
        int r = 0;
        for (int i = 0; i < 16; ++i) { const int t = wsum[i]; wsum[i] = r; r += t; }
    }
    __syncthreads();
    const int excl = v - s + wsum[wid];
#pragma unroll
    for (int i = 0; i < CH; ++i) {
        const int idx = base + i;
        if (idx < N_NODES) row_start[idx] = excl + local[i];
    }
    if (tid == 1023) row_start[N_NODES] = excl + s;
}

__global__ void fill_csr(const int* __restrict__ dst, const int* __restrict__ src,
                         const float* __restrict__ ea,
                         const int* __restrict__ row_start,
                         int* __restrict__ cursor, int2* __restrict__ ekv)
{
    const int e = blockIdx.x * 256 + threadIdx.x;
    if (e < N_EDGES) {
        const int d = dst[e];
        const int p = atomicAdd(&cursor[d], 1);
        int2 pk;
        pk.x = src[e];
        pk.y = __float_as_int(ea[e]);
        ekv[row_start[d] + p] = pk;
    }
}

// ---------------- attention: single pass, 2-edge unroll ----------------
__global__ __launch_bounds__(256) void attn_k(const float* __restrict__ q,
                                              const unsigned short* __restrict__ kb,
                                              const unsigned short* __restrict__ vb,
                                              const float* __restrict__ We,
                                              const int* __restrict__ row_start,
                                              const int2* __restrict__ ekv,
                                              float* __restrict__ out)
{
    const int wid  = threadIdx.x >> 6;
    const int lane = threadIdx.x & 63;
    const int n = blockIdx.x * 4 + wid;
    if (n >= N_NODES) return;

    const float4 qf  = *(const float4*)(q + (size_t)n * 256 + lane * 4);
    const float4 we4 = *(const float4*)(We + lane * 4);
    const int rs = row_start[n], re = row_start[n + 1];

    float ssum = 0.f;
    float ax = 0.f, ay = 0.f, az = 0.f, aw = 0.f;

    int s = rs;
    for (; s + 2 <= re; s += 2) {
        const int2 p0 = ekv[s];
        const int2 p1 = ekv[s + 1];
        int sn0 = p0.x, sn1 = p1.x;
        sn0 = ((unsigned)sn0 < N_NODES) ? sn0 : 0;   // defensive clamp
        sn1 = ((unsigned)sn1 < N_NODES) ? sn1 : 0;
        const float a0 = __int_as_float(p0.y), a1 = __int_as_float(p1.y);
        const ushort4 k0 = *(const ushort4*)(kb + (size_t)sn0 * 256 + lane * 4);
        const ushort4 v0 = *(const ushort4*)(vb + (size_t)sn0 * 256 + lane * 4);
        const ushort4 k1 = *(const ushort4*)(kb + (size_t)sn1 * 256 + lane * 4);
        const ushort4 v1 = *(const ushort4*)(vb + (size_t)sn1 * 256 + lane * 4);

        float p = qf.x * (b2f(k0.x) + a0 * we4.x) + qf.y * (b2f(k0.y) + a0 * we4.y)
                + qf.z * (b2f(k0.z) + a0 * we4.z) + qf.w * (b2f(k0.w) + a0 * we4.w);
        p += __shfl_xor(p, 1); p += __shfl_xor(p, 2);
        p += __shfl_xor(p, 4); p += __shfl_xor(p, 8);
        float wgt = __expf(p * 0.125f);
        ssum += wgt;
        ax += wgt * (b2f(v0.x) + a0 * we4.x);
        ay += wgt * (b2f(v0.y) + a0 * we4.y);
        az += wgt * (b2f(v0.z) + a0 * we4.z);
        aw += wgt * (b2f(v0.w) + a0 * we4.w);

        p = qf.x * (b2f(k1.x) + a1 * we4.x) + qf.y * (b2f(k1.y) + a1 * we4.y)
          + qf.z * (b2f(k1.z) + a1 * we4.z) + qf.w * (b2f(k1.w) + a1 * we4.w);
        p += __shfl_xor(p, 1); p += __shfl_xor(p, 2);
        p += __shfl_xor(p, 4); p += __shfl_xor(p, 8);
        wgt = __expf(p * 0.125f);
        ssum += wgt;
        ax += wgt * (b2f(v1.x) + a1 * we4.x);
        ay += wgt * (b2f(v1.y) + a1 * we4.y);
        az += wgt * (b2f(v1.z) + a1 * we4.z);
        aw += wgt * (b2f(v1.w) + a1 * we4.w);
    }
    if (s < re) {
        const int2 p0 = ekv[s];
        int sn0 = p0.x;
        sn0 = ((unsigned)sn0 < N_NODES) ? sn0 : 0;
        const float a0 = __int_as_float(p0.y);
        const ushort4 k0 = *(const ushort4*)(kb + (size_t)sn0 * 256 + lane * 4);
        const ushort4 v0 = *(const ushort4*)(vb + (size_t)sn0 * 256 + lane * 4);
        float p = qf.x * (b2f(k0.x) + a0 * we4.x) + qf.y * (b2f(k0.y) + a0 * we4.y)
                + qf.z * (b2f(k0.z) + a0 * we4.z) + qf.w * (b2f(k0.w) + a0 * we4.w);
        p += __shfl_xor(p, 1); p += __shfl_xor(p, 2);
        p += __shfl_xor(p, 4); p += __shfl_xor(p, 8);
        const float wgt = __expf(p * 0.125f);
        ssum += wgt;
        ax += wgt * (b2f(v0.x) + a0 * we4.x);
        ay += wgt * (b2f(v0.y) + a0 * we4.y);
        az += wgt * (b2f(v0.z) + a0 * we4.z);
        aw += wgt * (b2f(v0.w) + a0 * we4.w);
    }
    const float inv = 1.f / (ssum + 1e-16f);
    const float4 sk = *(const float4*)(out + (size_t)n * 256 + lane * 4);
    float4 o;
    o.x = ax * inv + sk.x;
    o.y = ay * inv + sk.y;
    o.z = az * inv + sk.z;
    o.w = aw * inv + sk.w;
    *(float4*)(out + (size_t)n * 256 + lane * 4) = o;
}

// ---------------- GraphNorm stats ----------------
__global__ __launch_bounds__(256) void gn_stats_k(const float* __restrict__ out,
                                                  float* __restrict__ gstats)
{
    const int c = threadIdx.x;
    float s = 0.f, s2 = 0.f;
    for (int r = blockIdx.x; r < N_NODES; r += gridDim.x) {
        const float vv = out[(size_t)r * 256 + c];
        s += vv; s2 += vv * vv;
    }
    atomicAdd(&gstats[c], s);
    atomicAdd(&gstats[256 + c], s2);
}

// ---------------- norm + relu + bf16 transpose: obT[256][SK] ----------------
__global__ __launch_bounds__(256) void norm_relu_T(const float* __restrict__ ob,
                                                   const float* __restrict__ gstats,
                                                   const float* __restrict__ gw,
                                                   const float* __restrict__ gb,
                                                   const float* __restrict__ gms,
                                                   unsigned short* __restrict__ obT)
{
    __shared__ unsigned short tile[256][72];   // [col][row], 16B-aligned rows (144B)
    __shared__ float smu[256], swi[256], sbd[256];
    const int t = threadIdx.x;
    const int r0 = blockIdx.x * 64;
    {
        const float invN = 1.f / (float)N_NODES;
        const float mean = gstats[t] * invN;
        const float exx  = gstats[256 + t] * invN;
        const float mu   = gms[t] * mean;
        const float var  = exx - 2.f * mu * mean + mu * mu;
        smu[t] = mu;
        swi[t] = gw[t] * rsqrtf(var + 1e-5f);
        sbd[t] = gb[t];
    }
    __syncthreads();
    const int rr = t >> 2;
    const int row = r0 + rr;
#pragma unroll
    for (int it = 0; it < 16; ++it) {
        const int col = it * 16 + (t & 3) * 4;
        float4 f = make_float4(0.f, 0.f, 0.f, 0.f);
        if (row < N_NODES) f = *(const float4*)(ob + (size_t)row * 256 + col);
        ushort4 u;
        if (row < N_NODES) {
            u.x = f2bf(fmaxf((f.x - smu[col + 0]) * swi[col + 0] + sbd[col + 0], 0.f));
            u.y = f2bf(fmaxf((f.y - smu[col + 1]) * swi[col + 1] + sbd[col + 1], 0.f));
            u.z = f2bf(fmaxf((f.z - smu[col + 2]) * swi[col + 2] + sbd[col + 2], 0.f));
            u.w = f2bf(fmaxf((f.w - smu[col + 3]) * swi[col + 3] + sbd[col + 3], 0.f));
        } else { u.x = u.y = u.z = u.w = 0; }
        tile[col + 0][rr] = u.x;
        tile[col + 1][rr] = u.y;
        tile[col + 2][rr] = u.z;
        tile[col + 3][rr] = u.w;
    }
    __syncthreads();
    // write transposed: 8 ushorts (16B) per lane, 128B-contiguous per 8-lane group
#pragma unroll
    for (int it = 0; it < 8; ++it) {
        const int c = it * 32 + (t >> 3);
        const int part = t & 7;
        const uint4 x0 = *(const uint4*)&tile[c][part * 8];
        *(uint4*)(obT + (size_t)c * SK + r0 + part * 8) = x0;
    }
}

// ---------------- Gram: xt = P^T P via bf16 MFMA on obT (NT layout) ----------------
// (fixed: uint4 loads = 8 bf16 each; 4 loads cover the full 32-elem kseg)
__global__ __launch_bounds__(256) void gram_k(const unsigned short* __restrict__ obT,
                                              float* __restrict__ xt)
{
    const int bi_l[10] = {0,0,0,0,1,1,1,2,2,3};
    const int bj_l[10] = {0,1,2,3,1,2,3,2,3,3};
    const int bi = bi_l[blockIdx.x], bj = bj_l[blockIdx.x];
    const int r0 = blockIdx.y * 1024;        // K chunk (SK/20 = 1024)

    __shared__ __align__(16) unsigned short Ai[64 * 136];
    __shared__ __align__(16) unsigned short Aj[64 * 136];
    const int tid = threadIdx.x;
    const int lane = tid & 63;
    const int w = tid >> 6;                  // 4 waves, 2x2
    const int wi = w >> 1, wj = w & 1;
    const int lr = tid >> 2, kseg = (tid & 3) * 32;
    const int fr = lane & 15, fk = (lane >> 4) * 8, lg = lane >> 4;

    f32x4 acc[2][2] = {};

    for (int kt = 0; kt < 1024; kt += 128) {
        uint4 ai[4], aj[4];
        const unsigned short* pa = obT + (size_t)(bi * 64 + lr) * SK + r0 + kt + kseg;
        const unsigned short* pb = obT + (size_t)(bj * 64 + lr) * SK + r0 + kt + kseg;
#pragma unroll
        for (int j = 0; j < 4; ++j) { ai[j] = *(const uint4*)(pa + 8 * j); aj[j] = *(const uint4*)(pb + 8 * j); }
        __syncthreads();
#pragma unroll
        for (int j = 0; j < 4; ++j) {
            *(uint4*)&Ai[lr * 136 + kseg + 8 * j] = ai[j];
            *(uint4*)&Aj[lr * 136 + kseg + 8 * j] = aj[j];
        }
        __syncthreads();
#pragma unroll
        for (int ks = 0; ks < 4; ++ks) {
            short8 af[2], bf[2];
#pragma unroll
            for (int m = 0; m < 2; ++m)
                af[m] = *(const short8*)&Ai[(wi * 32 + m * 16 + fr) * 136 + ks * 32 + fk];
#pragma unroll
            for (int n = 0; n < 2; ++n)
                bf[n] = *(const short8*)&Aj[(wj * 32 + n * 16 + fr) * 136 + ks * 32 + fk];
#pragma unroll
            for (int m = 0; m < 2; ++m)
#pragma unroll
                for (int n = 0; n < 2; ++n)
                    acc[m][n] = __builtin_amdgcn_mfma_f32_16x16x32_bf16(af[m], bf[n], acc[m][n], 0, 0, 0);
        }
    }
#pragma unroll
    for (int m = 0; m < 2; ++m)
#pragma unroll
        for (int n = 0; n < 2; ++n)
#pragma unroll
            for (int r = 0; r < 4; ++r)
                atomicAdd(&xt[(size_t)(bi * 64 + wi * 32 + m * 16 + lg * 4 + r) * 256
                              + bj * 64 + wj * 32 + n * 16 + fr], acc[m][n][r]);
}

// ---------------- min/max over upper blocks + finalize w/ mirror ----------------
__global__ __launch_bounds__(1024) void minmax_k(const float* __restrict__ xt,
                                                 float* __restrict__ mm)
{
    const int tid = threadIdx.x;
    float mn = 1e30f, mx = -1e30f;
    for (int i = tid; i < 65536; i += 1024) {
        const int r = i >> 8, c = i & 255;
        if ((r >> 6) <= (c >> 6)) {
            const float v = xt[i];
            mn = fminf(mn, v);
            mx = fmaxf(mx, v);
        }
    }
    for (int off = 1; off < 64; off <<= 1) {
        mn = fminf(mn, __shfl_xor(mn, off));
        mx = fmaxf(mx, __shfl_xor(mx, off));
    }
    __shared__ float smn[16], smx[16];
    const int w = tid >> 6;
    if ((tid & 63) == 0) { smn[w] = mn; smx[w] = mx; }
    __syncthreads();
    if (tid == 0) {
        for (int i = 1; i < 16; ++i) {
            mn = fminf(mn, smn[i]);
            mx = fmaxf(mx, smx[i]);
        }
        mm[0] = mn; mm[1] = mx;
    }
}

__global__ void finalize_k(const float* __restrict__ xt, const float* __restrict__ mm,
                           float* __restrict__ outp)
{
    const int i = blockIdx.x * 256 + threadIdx.x;
    const int r = i >> 8, c = i & 255;
    const float v = ((r >> 6) <= (c >> 6)) ? xt[i] : xt[c * 256 + r];
    const float mn = mm[0], mx = mm[1];
    const float inv = 1.f / (mx - mn + 1e-8f);
    outp[i] = (v - mn) * inv;
}

// ---------------- launch ----------------
extern "C" void kernel_launch(void* const* d_in, const int* in_sizes, int n_in,
                              void* d_out, int out_size, void* d_ws, size_t ws_size,
                              hipStream_t stream)
{
    (void)in_sizes; (void)n_in; (void)out_size; (void)ws_size;
    const float* x   = (const float*)d_in[0];
    const int*   ei  = (const int*)d_in[1];
    const float* ea  = (const float*)d_in[2];
    const float* Wq  = (const float*)d_in[3];
    const float* bq  = (const float*)d_in[4];
    const float* Wk  = (const float*)d_in[5];
    const float* bk  = (const float*)d_in[6];
    const float* Wv  = (const float*)d_in[7];
    const float* bv  = (const float*)d_in[8];
    const float* We  = (const float*)d_in[9];
    const float* Wsk = (const float*)d_in[10];
    const float* bsk = (const float*)d_in[11];
    const float* gw  = (const float*)d_in[12];
    const float* gb  = (const float*)d_in[13];
    const float* gms = (const float*)d_in[14];
    float* outp = (float*)d_out;

    char* ws = (char*)d_ws;
    size_t off = 0;
    // every allocation 256B-aligned; overlays keep total under the round-2-proven size
    #define WS_ALLOC(nbytes) (ws + off); off = (off + (size_t)(nbytes) + 255) & ~(size_t)255
    unsigned short* xb = (unsigned short*)WS_ALLOC((size_t)N_NODES * 256 * 2);   // dead after gemm -> hosts ekv
    unsigned short* wT = (unsigned short*)WS_ALLOC((size_t)1024 * 256 * 2);
    float* bias_all    = (float*)WS_ALLOC(1024 * 4);
    float* qb          = (float*)WS_ALLOC((size_t)N_NODES * 256 * 4);            // dead after attn -> hosts obT
    unsigned short* kb = (unsigned short*)WS_ALLOC((size_t)N_NODES * 256 * 2);
    unsigned short* vb = (unsigned short*)WS_ALLOC((size_t)N_NODES * 256 * 2);
    float* ob          = (float*)WS_ALLOC((size_t)N_NODES * 256 * 4);
    // ---- zero region (reset every call) ----
    const size_t zoff = off;
    int*   deg    = (int*)WS_ALLOC((size_t)N_NODES * 4);
    int*   cur    = (int*)WS_ALLOC((size_t)N_NODES * 4);
    float* gstats = (float*)WS_ALLOC(512 * 4);
    float* xt     = (float*)WS_ALLOC(65536 * 4);
    const size_t zbytes = off - zoff;
    // ---- end zero region ----
    int* row_start = (int*)WS_ALLOC((size_t)(N_NODES + 1) * 4);
    float* mm      = (float*)WS_ALLOC(2 * 4);
    #undef WS_ALLOC
    // overlays (regions dead by the time these are written)
    int2* ekv           = (int2*)xb;           // 2.56 MB in 10.24 MB region
    unsigned short* obT = (unsigned short*)qb; // 10.49 MB in 20.48 MB region

    const int* srcv = ei;            // edge_index[0]
    const int* dstv = ei + N_EDGES;  // edge_index[1]

    hipMemsetAsync(ws + zoff, 0, zbytes, stream);

    conv_x_k<<<(N_NODES * 256 / 8 + 255) / 256, 256, 0, stream>>>(x, xb);
    conv_w_k<<<1024, 256, 0, stream>>>(Wq, Wk, Wv, Wsk, bq, bk, bv, bsk, wT, bias_all);

    gemm_qkvs<<<dim3((N_NODES + 127) / 128, 4), 512, 0, stream>>>(xb, wT, bias_all,
                                                                  qb, kb, vb, ob);

    count_deg<<<(N_EDGES + 255) / 256, 256, 0, stream>>>(dstv, deg);
    scan_k<<<1, 1024, 0, stream>>>(deg, row_start);
    fill_csr<<<(N_EDGES + 255) / 256, 256, 0, stream>>>(dstv, srcv, ea, row_start, cur, ekv);

    attn_k<<<(N_NODES + 3) / 4, 256, 0, stream>>>(qb, kb, vb, We, row_start, ekv, ob);

    gn_stats_k<<<160, 256, 0, stream>>>(ob, gstats);
    norm_relu_T<<<320, 256, 0, stream>>>(ob, gstats, gw, gb, gms, obT);

    gram_k<<<dim3(10, 20), 256, 0, stream>>>(obT, xt);
    minmax_k<<<1, 1024, 0, stream>>>(xt, mm);
    finalize_k<<<256, 256, 0, stream>>>(xt, mm, outp);
}

// Round 8
// 226.520 us; speedup vs baseline: 2.3473x; 1.0395x over previous
//
#include <hip/hip_runtime.h>
#include <math.h>

#define N_NODES 20000
#define N_EDGES 320000
#define SK 20480   // zero-padded K (rows) for transposed gram operand

typedef short short8 __attribute__((ext_vector_type(8)));
typedef float f32x4 __attribute__((ext_vector_type(4)));

static __device__ __forceinline__ unsigned short f2bf(float f) {
    unsigned int u = __float_as_uint(f);
    u = (u + 0x7FFF + ((u >> 16) & 1)) >> 16;
    return (unsigned short)u;
}
static __device__ __forceinline__ float b2f(unsigned short u) {
    return __uint_as_float((unsigned int)u << 16);
}
static __device__ __forceinline__ float blo(unsigned int u) {
    return __uint_as_float(u << 16);
}
static __device__ __forceinline__ float bhi(unsigned int u) {
    return __uint_as_float(u & 0xFFFF0000u);
}

// ---------------- convert x -> bf16 ----------------
__global__ __launch_bounds__(256) void conv_x_k(const float* __restrict__ x,
                                                unsigned short* __restrict__ xb)
{
    const int t8 = blockIdx.x * 256 + threadIdx.x;
    const size_t base = (size_t)t8 * 8;
    if (base >= (size_t)N_NODES * 256) return;
    const float4 f0 = *(const float4*)(x + base);
    const float4 f1 = *(const float4*)(x + base + 4);
    ushort4 u0, u1;
    u0.x = f2bf(f0.x); u0.y = f2bf(f0.y); u0.z = f2bf(f0.z); u0.w = f2bf(f0.w);
    u1.x = f2bf(f1.x); u1.y = f2bf(f1.y); u1.z = f2bf(f1.z); u1.w = f2bf(f1.w);
    *(ushort4*)(xb + base) = u0;
    *(ushort4*)(xb + base + 4) = u1;
}

// ---------------- build wT bf16 [1024][256] + bias_all ----------------
__global__ __launch_bounds__(256) void conv_w_k(const float* __restrict__ Wq,
                                                const float* __restrict__ Wk,
                                                const float* __restrict__ Wv,
                                                const float* __restrict__ Wsk,
                                                const float* __restrict__ bq,
                                                const float* __restrict__ bk,
                                                const float* __restrict__ bv,
                                                const float* __restrict__ bsk,
                                                unsigned short* __restrict__ wT,
                                                float* __restrict__ bias_all)
{
    const int b = blockIdx.x;          // 0..1023 : wi*256 + n
    const int kk = threadIdx.x;        // 0..255
    const int wi = b >> 8, n = b & 255;
    const float* W = (wi == 0) ? Wq : (wi == 1) ? Wk : (wi == 2) ? Wv : Wsk;
    wT[(size_t)b * 256 + kk] = f2bf(W[(size_t)kk * 256 + n]);
    if (kk == 0) {
        const float* bb = (wi == 0) ? bq : (wi == 1) ? bk : (wi == 2) ? bv : bsk;
        bias_all[b] = bb[n];
    }
}

// ---------------- fused QKVS GEMM: tile 128x256, LDS-staged coalesced epilogue ----------------
__global__ __launch_bounds__(512, 2) void gemm_qkvs(const unsigned short* __restrict__ xb,
                                                    const unsigned short* __restrict__ wT,
                                                    const float* __restrict__ bias_all,
                                                    float* __restrict__ qb,
                                                    unsigned short* __restrict__ kvb,
                                                    float* __restrict__ ob)
{
    __shared__ __align__(16) unsigned short As[(128 + 256) * 80];   // As(128x80) then Bs(256x80)
    unsigned short* Bs = As + 128 * 80;
    float* stage = (float*)As;                                      // reused after K-loop

    const int tid  = threadIdx.x;
    const int lane = tid & 63;
    const int w    = tid >> 6;         // 0..7
    const int wm = w >> 2, wn = w & 3; // wave grid 2x4 (64-row x 64-col per wave)
    const int row0 = blockIdx.x * 128;
    const int wsel = blockIdx.y;       // 0=q 1=k 2=v 3=skip
    const int colG = wsel * 256;
    const int ar = tid >> 2, ak = (tid & 3) * 16;   // A: 128 rows x 16 k-elems
    const int br = tid >> 1, bk = (tid & 1) * 32;   // B: 256 rows x 32 k-elems
    const int fr = lane & 15, fk = (lane >> 4) * 8, lg = lane >> 4;

    f32x4 acc[4][4] = {};

    for (int k0 = 0; k0 < 256; k0 += 64) {
        int gr = row0 + ar; gr = gr < N_NODES ? gr : N_NODES - 1;
        const unsigned short* ap = xb + (size_t)gr * 256 + k0 + ak;
        const uint4 a0 = *(const uint4*)ap;          // elems [0..7]
        const uint4 a1 = *(const uint4*)(ap + 8);    // elems [8..15]
        const unsigned short* bp = wT + (size_t)(colG + br) * 256 + k0 + bk;
        const uint4 b0 = *(const uint4*)bp;
        const uint4 b1 = *(const uint4*)(bp + 8);
        const uint4 b2 = *(const uint4*)(bp + 16);
        const uint4 b3 = *(const uint4*)(bp + 24);
        __syncthreads();
        *(uint4*)&As[ar * 80 + ak]     = a0;
        *(uint4*)&As[ar * 80 + ak + 8] = a1;
        unsigned short* bsp = &Bs[br * 80 + bk];
        *(uint4*)bsp        = b0;
        *(uint4*)(bsp + 8)  = b1;
        *(uint4*)(bsp + 16) = b2;
        *(uint4*)(bsp + 24) = b3;
        __syncthreads();
#pragma unroll
        for (int ks = 0; ks < 2; ++ks) {
            short8 af[4], bf[4];
#pragma unroll
            for (int m = 0; m < 4; ++m)
                af[m] = *(const short8*)&As[(wm * 64 + m * 16 + fr) * 80 + ks * 32 + fk];
#pragma unroll
            for (int n = 0; n < 4; ++n)
                bf[n] = *(const short8*)&Bs[(wn * 64 + n * 16 + fr) * 80 + ks * 32 + fk];
#pragma unroll
            for (int m = 0; m < 4; ++m)
#pragma unroll
                for (int n = 0; n < 4; ++n)
                    acc[m][n] = __builtin_amdgcn_mfma_f32_16x16x32_bf16(af[m], bf[n], acc[m][n], 0, 0, 0);
        }
    }
    __syncthreads();                   // all frag reads done; LDS reusable

    float badd[4];
#pragma unroll
    for (int n = 0; n < 4; ++n) badd[n] = bias_all[colG + wn * 64 + n * 16 + fr];

    float* st = stage + w * 1024;      // 4 KB wave-private staging (16 rows x 64 cols)
#pragma unroll
    for (int m = 0; m < 4; ++m) {
#pragma unroll
        for (int n = 0; n < 4; ++n)
#pragma unroll
            for (int r = 0; r < 4; ++r)
                st[(lg * 4 + r) * 64 + n * 16 + fr] = acc[m][n][r] + badd[n];
#pragma unroll
        for (int it = 0; it < 4; ++it) {
            const int lrow = it * 4 + lg;
            const f32x4 c4 = *(const f32x4*)&st[lrow * 64 + fr * 4];
            const int grow = row0 + wm * 64 + m * 16 + lrow;
            if (grow < N_NODES) {
                if (wsel == 0) {
                    float4 o; o.x = c4[0]; o.y = c4[1]; o.z = c4[2]; o.w = c4[3];
                    *(float4*)(qb + (size_t)grow * 256 + wn * 64 + fr * 4) = o;
                } else if (wsel == 3) {
                    float4 o; o.x = c4[0]; o.y = c4[1]; o.z = c4[2]; o.w = c4[3];
                    *(float4*)(ob + (size_t)grow * 256 + wn * 64 + fr * 4) = o;
                } else {
                    // interleaved kv: chunk c=(wn*16+fr) holds k[4c..4c+3] then v[4c..4c+3]
                    ushort4 u;
                    u.x = f2bf(c4[0]); u.y = f2bf(c4[1]); u.z = f2bf(c4[2]); u.w = f2bf(c4[3]);
                    const size_t kvidx = (size_t)grow * 512 + (wn * 16 + fr) * 8 + (wsel == 1 ? 0 : 4);
                    *(ushort4*)(kvb + kvidx) = u;
                }
            }
        }
    }
}

// ---------------- CSR build ----------------
__global__ void count_deg(const int* __restrict__ dst, int* __restrict__ deg)
{
    const int e = blockIdx.x * 256 + threadIdx.x;
    if (e < N_EDGES) atomicAdd(&deg[dst[e]], 1);
}

__global__ __launch_bounds__(1024) void scan_k(const int* __restrict__ deg,
                                               int* __restrict__ row_start)
{
    __shared__ int sdeg[20480];          // 80 KB: coalesced staging
    const int tid = threadIdx.x;
    const int lane = tid & 63, wid = tid >> 6;
    const int CH = 20;
#pragma unroll
    for (int i = 0; i < 20; ++i) {
        const int idx = i * 1024 + tid;
        sdeg[idx] = (idx < N_NODES) ? deg[idx] : 0;
    }
    __syncthreads();
    const int base = tid * CH;
    int local[CH];
    int s = 0;
#pragma unroll
    for (int i = 0; i < CH; ++i) {
        local[i] = s;
        s += sdeg[base + i];
    }
    int v = s;
#pragma unroll
    for (int off = 1; off < 64; off <<= 1) {
        const int t = __shfl_up(v, off);
        if (lane >= off) v += t;
    }
    __shared__ int wsum[16];
    if (lane == 63) wsum[wid] = v;
    __syncthreads();
    if (tid == 0) {
        int r = 0;
        for (int i = 0; i < 16; ++i) { const int t = wsum[i]; wsum[i] = r; r += t; }
    }
    __syncthreads();
    const int excl = v - s + wsum[wid];
#pragma unroll
    for (int i = 0; i < CH; ++i) {
        const int idx = base + i;
        if (idx < N_NODES) row_start[idx] = excl + local[i];
    }
    if (tid == 1023) row_start[N_NODES] = excl + s;
}

__global__ void fill_csr(const int* __restrict__ dst, const int* __restrict__ src,
                         const float* __restrict__ ea,
                         const int* __restrict__ row_start,
                         int* __restrict__ cursor, int2* __restrict__ ekv)
{
    const int e = blockIdx.x * 256 + threadIdx.x;
    if (e < N_EDGES) {
        const int d = dst[e];
        const int p = atomicAdd(&cursor[d], 1);
        int2 pk;
        pk.x = src[e];
        pk.y = __float_as_int(ea[e]);
        ekv[row_start[d] + p] = pk;
    }
}

// ---------------- attention: single pass, interleaved kv, 4-edge unroll ----------------
static __device__ __forceinline__ void edge_step(const uint4 kv, const float a,
                                                 const float4 qf, const float4 we4,
                                                 float& ssum, float& ax, float& ay,
                                                 float& az, float& aw)
{
    const float k0 = blo(kv.x), k1 = bhi(kv.x), k2 = blo(kv.y), k3 = bhi(kv.y);
    const float v0 = blo(kv.z), v1 = bhi(kv.z), v2 = blo(kv.w), v3 = bhi(kv.w);
    float p = qf.x * (k0 + a * we4.x) + qf.y * (k1 + a * we4.y)
            + qf.z * (k2 + a * we4.z) + qf.w * (k3 + a * we4.w);
    p += __shfl_xor(p, 1); p += __shfl_xor(p, 2);
    p += __shfl_xor(p, 4); p += __shfl_xor(p, 8);
    const float wgt = __expf(p * 0.125f);
    ssum += wgt;
    ax += wgt * (v0 + a * we4.x);
    ay += wgt * (v1 + a * we4.y);
    az += wgt * (v2 + a * we4.z);
    aw += wgt * (v3 + a * we4.w);
}

__global__ __launch_bounds__(256) void attn_k(const float* __restrict__ q,
                                              const unsigned short* __restrict__ kvb,
                                              const float* __restrict__ We,
                                              const int* __restrict__ row_start,
                                              const int2* __restrict__ ekv,
                                              float* __restrict__ out)
{
    const int wid  = threadIdx.x >> 6;
    const int lane = threadIdx.x & 63;
    const int n = blockIdx.x * 4 + wid;
    if (n >= N_NODES) return;

    const float4 qf  = *(const float4*)(q + (size_t)n * 256 + lane * 4);
    const float4 we4 = *(const float4*)(We + lane * 4);
    const int rs = row_start[n], re = row_start[n + 1];
    const int lo8 = lane * 8;

    float ssum = 0.f;
    float ax = 0.f, ay = 0.f, az = 0.f, aw = 0.f;

    int s = rs;
    for (; s + 4 <= re; s += 4) {
        const int2 p0 = ekv[s],     p1 = ekv[s + 1];
        const int2 p2 = ekv[s + 2], p3 = ekv[s + 3];
        const int sn0 = ((unsigned)p0.x < N_NODES) ? p0.x : 0;
        const int sn1 = ((unsigned)p1.x < N_NODES) ? p1.x : 0;
        const int sn2 = ((unsigned)p2.x < N_NODES) ? p2.x : 0;
        const int sn3 = ((unsigned)p3.x < N_NODES) ? p3.x : 0;
        const uint4 kv0 = *(const uint4*)(kvb + (size_t)sn0 * 512 + lo8);
        const uint4 kv1 = *(const uint4*)(kvb + (size_t)sn1 * 512 + lo8);
        const uint4 kv2 = *(const uint4*)(kvb + (size_t)sn2 * 512 + lo8);
        const uint4 kv3 = *(const uint4*)(kvb + (size_t)sn3 * 512 + lo8);
        edge_step(kv0, __int_as_float(p0.y), qf, we4, ssum, ax, ay, az, aw);
        edge_step(kv1, __int_as_float(p1.y), qf, we4, ssum, ax, ay, az, aw);
        edge_step(kv2, __int_as_float(p2.y), qf, we4, ssum, ax, ay, az, aw);
        edge_step(kv3, __int_as_float(p3.y), qf, we4, ssum, ax, ay, az, aw);
    }
    for (; s < re; ++s) {
        const int2 p0 = ekv[s];
        const int sn0 = ((unsigned)p0.x < N_NODES) ? p0.x : 0;
        const uint4 kv0 = *(const uint4*)(kvb + (size_t)sn0 * 512 + lo8);
        edge_step(kv0, __int_as_float(p0.y), qf, we4, ssum, ax, ay, az, aw);
    }
    const float inv = 1.f / (ssum + 1e-16f);
    const float4 sk = *(const float4*)(out + (size_t)n * 256 + lane * 4);
    float4 o;
    o.x = ax * inv + sk.x;
    o.y = ay * inv + sk.y;
    o.z = az * inv + sk.z;
    o.w = aw * inv + sk.w;
    *(float4*)(out + (size_t)n * 256 + lane * 4) = o;
}

// ---------------- GraphNorm stats ----------------
__global__ __launch_bounds__(256) void gn_stats_k(const float* __restrict__ out,
                                                  float* __restrict__ gstats)
{
    const int c = threadIdx.x;
    float s = 0.f, s2 = 0.f;
    for (int r = blockIdx.x; r < N_NODES; r += gridDim.x) {
        const float vv = out[(size_t)r * 256 + c];
        s += vv; s2 += vv * vv;
    }
    atomicAdd(&gstats[c], s);
    atomicAdd(&gstats[256 + c], s2);
}

// ---------------- norm + relu + bf16 transpose: obT[256][SK] ----------------
__global__ __launch_bounds__(256) void norm_relu_T(const float* __restrict__ ob,
                                                   const float* __restrict__ gstats,
                                                   const float* __restrict__ gw,
                                                   const float* __restrict__ gb,
                                                   const float* __restrict__ gms,
                                                   unsigned short* __restrict__ obT)
{
    __shared__ unsigned short tile[256][72];   // [col][row], 16B-aligned rows (144B)
    __shared__ float smu[256], swi[256], sbd[256];
    const int t = threadIdx.x;
    const int r0 = blockIdx.x * 64;
    {
        const float invN = 1.f / (float)N_NODES;
        const float mean = gstats[t] * invN;
        const float exx  = gstats[256 + t] * invN;
        const float mu   = gms[t] * mean;
        const float var  = exx - 2.f * mu * mean + mu * mu;
        smu[t] = mu;
        swi[t] = gw[t] * rsqrtf(var + 1e-5f);
        sbd[t] = gb[t];
    }
    __syncthreads();
    const int rr = t >> 2;
    const int row = r0 + rr;
#pragma unroll
    for (int it = 0; it < 16; ++it) {
        const int col = it * 16 + (t & 3) * 4;
        float4 f = make_float4(0.f, 0.f, 0.f, 0.f);
        if (row < N_NODES) f = *(const float4*)(ob + (size_t)row * 256 + col);
        ushort4 u;
        if (row < N_NODES) {
            u.x = f2bf(fmaxf((f.x - smu[col + 0]) * swi[col + 0] + sbd[col + 0], 0.f));
            u.y = f2bf(fmaxf((f.y - smu[col + 1]) * swi[col + 1] + sbd[col + 1], 0.f));
            u.z = f2bf(fmaxf((f.z - smu[col + 2]) * swi[col + 2] + sbd[col + 2], 0.f));
            u.w = f2bf(fmaxf((f.w - smu[col + 3]) * swi[col + 3] + sbd[col + 3], 0.f));
        } else { u.x = u.y = u.z = u.w = 0; }
        tile[col + 0][rr] = u.x;
        tile[col + 1][rr] = u.y;
        tile[col + 2][rr] = u.z;
        tile[col + 3][rr] = u.w;
    }
    __syncthreads();
#pragma unroll
    for (int it = 0; it < 8; ++it) {
        const int c = it * 32 + (t >> 3);
        const int part = t & 7;
        const uint4 x0 = *(const uint4*)&tile[c][part * 8];
        *(uint4*)(obT + (size_t)c * SK + r0 + part * 8) = x0;
    }
}

// ---------------- Gram: xt = P^T P via bf16 MFMA on obT (NT layout) ----------------
__global__ __launch_bounds__(256) void gram_k(const unsigned short* __restrict__ obT,
                                              float* __restrict__ xt)
{
    const int bi_l[10] = {0,0,0,0,1,1,1,2,2,3};
    const int bj_l[10] = {0,1,2,3,1,2,3,2,3,3};
    const int bi = bi_l[blockIdx.x], bj = bj_l[blockIdx.x];
    const int r0 = blockIdx.y * 1024;        // K chunk (SK/20 = 1024)

    __shared__ __align__(16) unsigned short Ai[64 * 136];
    __shared__ __align__(16) unsigned short Aj[64 * 136];
    const int tid = threadIdx.x;
    const int lane = tid & 63;
    const int w = tid >> 6;                  // 4 waves, 2x2
    const int wi = w >> 1, wj = w & 1;
    const int lr = tid >> 2, kseg = (tid & 3) * 32;
    const int fr = lane & 15, fk = (lane >> 4) * 8, lg = lane >> 4;

    f32x4 acc[2][2] = {};

    for (int kt = 0; kt < 1024; kt += 128) {
        uint4 ai[4], aj[4];
        const unsigned short* pa = obT + (size_t)(bi * 64 + lr) * SK + r0 + kt + kseg;
        const unsigned short* pb = obT + (size_t)(bj * 64 + lr) * SK + r0 + kt + kseg;
#pragma unroll
        for (int j = 0; j < 4; ++j) { ai[j] = *(const uint4*)(pa + 8 * j); aj[j] = *(const uint4*)(pb + 8 * j); }
        __syncthreads();
#pragma unroll
        for (int j = 0; j < 4; ++j) {
            *(uint4*)&Ai[lr * 136 + kseg + 8 * j] = ai[j];
            *(uint4*)&Aj[lr * 136 + kseg + 8 * j] = aj[j];
        }
        __syncthreads();
#pragma unroll
        for (int ks = 0; ks < 4; ++ks) {
            short8 af[2], bf[2];
#pragma unroll
            for (int m = 0; m < 2; ++m)
                af[m] = *(const short8*)&Ai[(wi * 32 + m * 16 + fr) * 136 + ks * 32 + fk];
#pragma unroll
            for (int n = 0; n < 2; ++n)
                bf[n] = *(const short8*)&Aj[(wj * 32 + n * 16 + fr) * 136 + ks * 32 + fk];
#pragma unroll
            for (int m = 0; m < 2; ++m)
#pragma unroll
                for (int n = 0; n < 2; ++n)
                    acc[m][n] = __builtin_amdgcn_mfma_f32_16x16x32_bf16(af[m], bf[n], acc[m][n], 0, 0, 0);
        }
    }
#pragma unroll
    for (int m = 0; m < 2; ++m)
#pragma unroll
        for (int n = 0; n < 2; ++n)
#pragma unroll
            for (int r = 0; r < 4; ++r)
                atomicAdd(&xt[(size_t)(bi * 64 + wi * 32 + m * 16 + lg * 4 + r) * 256
                              + bj * 64 + wj * 32 + n * 16 + fr], acc[m][n][r]);
}

// ---------------- min/max over upper blocks + finalize w/ mirror ----------------
__global__ __launch_bounds__(1024) void minmax_k(const float* __restrict__ xt,
                                                 float* __restrict__ mm)
{
    const int tid = threadIdx.x;
    float mn = 1e30f, mx = -1e30f;
    for (int i = tid; i < 65536; i += 1024) {
        const int r = i >> 8, c = i & 255;
        if ((r >> 6) <= (c >> 6)) {
            const float v = xt[i];
            mn = fminf(mn, v);
            mx = fmaxf(mx, v);
        }
    }
    for (int off = 1; off < 64; off <<= 1) {
        mn = fminf(mn, __shfl_xor(mn, off));
        mx = fmaxf(mx, __shfl_xor(mx, off));
    }
    __shared__ float smn[16], smx[16];
    const int w = tid >> 6;
    if ((tid & 63) == 0) { smn[w] = mn; smx[w] = mx; }
    __syncthreads();
    if (tid == 0) {
        for (int i = 1; i < 16; ++i) {
            mn = fminf(mn, smn[i]);
            mx = fmaxf(mx, smx[i]);
        }
        mm[0] = mn; mm[1] = mx;
    }
}

__global__ void finalize_k(const float* __restrict__ xt, const float* __restrict__ mm,
                           float* __restrict__ outp)
{
    const int i = blockIdx.x * 256 + threadIdx.x;
    const int r = i >> 8, c = i & 255;
    const float v = ((r >> 6) <= (c >> 6)) ? xt[i] : xt[c * 256 + r];
    const float mn = mm[0], mx = mm[1];
    const float inv = 1.f / (mx - mn + 1e-8f);
    outp[i] = (v - mn) * inv;
}

// ---------------- launch ----------------
extern "C" void kernel_launch(void* const* d_in, const int* in_sizes, int n_in,
                              void* d_out, int out_size, void* d_ws, size_t ws_size,
                              hipStream_t stream)
{
    (void)in_sizes; (void)n_in; (void)out_size; (void)ws_size;
    const float* x   = (const float*)d_in[0];
    const int*   ei  = (const int*)d_in[1];
    const float* ea  = (const float*)d_in[2];
    const float* Wq  = (const float*)d_in[3];
    const float* bq  = (const float*)d_in[4];
    const float* Wk  = (const float*)d_in[5];
    const float* bk  = (const float*)d_in[6];
    const float* Wv  = (const float*)d_in[7];
    const float* bv  = (const float*)d_in[8];
    const float* We  = (const float*)d_in[9];
    const float* Wsk = (const float*)d_in[10];
    const float* bsk = (const float*)d_in[11];
    const float* gw  = (const float*)d_in[12];
    const float* gb  = (const float*)d_in[13];
    const float* gms = (const float*)d_in[14];
    float* outp = (float*)d_out;

    char* ws = (char*)d_ws;
    size_t off = 0;
    #define WS_ALLOC(nbytes) (ws + off); off = (off + (size_t)(nbytes) + 255) & ~(size_t)255
    unsigned short* xb  = (unsigned short*)WS_ALLOC((size_t)N_NODES * 256 * 2);   // dead after gemm -> hosts ekv
    unsigned short* wT  = (unsigned short*)WS_ALLOC((size_t)1024 * 256 * 2);
    float* bias_all     = (float*)WS_ALLOC(1024 * 4);
    float* qb           = (float*)WS_ALLOC((size_t)N_NODES * 256 * 4);            // dead after attn -> hosts obT
    unsigned short* kvb = (unsigned short*)WS_ALLOC((size_t)N_NODES * 512 * 2);   // interleaved k|v
    float* ob           = (float*)WS_ALLOC((size_t)N_NODES * 256 * 4);
    // ---- zero region (reset every call) ----
    const size_t zoff = off;
    int*   deg    = (int*)WS_ALLOC((size_t)N_NODES * 4);
    int*   cur    = (int*)WS_ALLOC((size_t)N_NODES * 4);
    float* gstats = (float*)WS_ALLOC(512 * 4);
    float* xt     = (float*)WS_ALLOC(65536 * 4);
    const size_t zbytes = off - zoff;
    // ---- end zero region ----
    int* row_start = (int*)WS_ALLOC((size_t)(N_NODES + 1) * 4);
    float* mm      = (float*)WS_ALLOC(2 * 4);
    #undef WS_ALLOC
    // overlays (regions dead by the time these are written)
    int2* ekv           = (int2*)xb;           // 2.56 MB in 10.24 MB region
    unsigned short* obT = (unsigned short*)qb; // 10.49 MB in 20.48 MB region

    const int* srcv = ei;            // edge_index[0]
    const int* dstv = ei + N_EDGES;  // edge_index[1]

    hipMemsetAsync(ws + zoff, 0, zbytes, stream);

    conv_x_k<<<(N_NODES * 256 / 8 + 255) / 256, 256, 0, stream>>>(x, xb);
    conv_w_k<<<1024, 256, 0, stream>>>(Wq, Wk, Wv, Wsk, bq, bk, bv, bsk, wT, bias_all);

    gemm_qkvs<<<dim3((N_NODES + 127) / 128, 4), 512, 0, stream>>>(xb, wT, bias_all,
                                                                  qb, kvb, ob);

    count_deg<<<(N_EDGES + 255) / 256, 256, 0, stream>>>(dstv, deg);
    scan_k<<<1, 1024, 0, stream>>>(deg, row_start);
    fill_csr<<<(N_EDGES + 255) / 256, 256, 0, stream>>>(dstv, srcv, ea, row_start, cur, ekv);

    attn_k<<<(N_NODES + 3) / 4, 256, 0, stream>>>(qb, kvb, We, row_start, ekv, ob);

    gn_stats_k<<<400, 256, 0, stream>>>(ob, gstats);
    norm_relu_T<<<320, 256, 0, stream>>>(ob, gstats, gw, gb, gms, obT);

    gram_k<<<dim3(10, 20), 256, 0, stream>>>(obT, xt);
    minmax_k<<<1, 1024, 0, stream>>>(xt, mm);
    finalize_k<<<256, 256, 0, stream>>>(xt, mm, outp);
}